// Round 2
// baseline (334.308 us; speedup 1.0000x reference)
//
#include <hip/hip_runtime.h>
#include <math.h>

// Problem constants
#define B_ 8
#define N_ 128
#define H_ 64
#define MH_ 128
#define D_ 4
#define TSTEPS 12

typedef __attribute__((ext_vector_type(8))) short bf16x8;
typedef __attribute__((ext_vector_type(4))) float f32x4;

__device__ __forceinline__ float fast_tanh(float x) {
    // tanh(x) = 1 - 2/(exp2(2*log2e*x)+1); saturates correctly at +-inf
    float t = __builtin_amdgcn_exp2f(x * 2.8853900817779268f);
    return 1.0f - 2.0f * __builtin_amdgcn_rcpf(t + 1.0f);
}
__device__ __forceinline__ float fast_sigmoid(float x) {
    float t = __builtin_amdgcn_exp2f(x * -1.4426950408889634f);
    return __builtin_amdgcn_rcpf(1.0f + t);
}
__device__ __forceinline__ unsigned short f2bf(float x) {
    unsigned u = __builtin_bit_cast(unsigned, x);
    u += 0x7fffu + ((u >> 16) & 1u);   // RNE
    return (unsigned short)(u >> 16);
}

// ---------------- workspace layout (float offsets) ----------------
constexpr int OFF_APT  = 0;                         // [B][j][i] = 131072
constexpr int OFF_P    = OFF_APT + 131072;          // 2 x [1024][128]
constexpr int OFF_Q    = OFF_P   + 2 * 131072;      // 2 x [1024][128]
constexpr int OFF_HP   = OFF_Q   + 2 * 131072;      // 2 x [1024][192] (hr|hi|hh)
constexpr int OFF_H    = OFF_HP  + 2 * 196608;      // 2 x [1024][64]
constexpr int OFF_AGG  = OFF_H   + 2 * 65536;       // [1024][64]
constexpr int OFF_WAM  = OFF_AGG + 65536;           // [192][64]  (WmrT|WmiT|WmnT)
constexpr int OFF_WPR  = OFF_WAM + 12288;           // [448][64]  (Wm1topT|Wm1botT|WhrT|WhiT|WhhT)
constexpr int OFF_WO1  = OFF_WPR + 28672;           // [64][64]
constexpr int OFF_WO2  = OFF_WO1 + 4096;            // [64][64]
constexpr int OFF_WO3  = OFF_WO2 + 4096;            // [4][64]
constexpr int OFF_WM2F = OFF_WO3 + 256;             // 8192 ushorts (bf16 B-fragments)
constexpr int OFF_SSE  = OFF_WM2F + 4096;           // 1 float accumulator

// ---------------- adjacency projection (transposed store) ----------------
__global__ void pre_adj(const float* __restrict__ A, float* __restrict__ ApT) {
    int bi = blockIdx.x;
    int b = bi >> 7, i = bi & 127;
    int j = threadIdx.x;
    float aij = A[(b * 128 + i) * 128 + j];
    float aji = A[(b * 128 + j) * 128 + i];
    float s = fast_sigmoid(0.5f * (aij + aji));
    if (j == i) s = 0.0f;
    float r = s;
    #pragma unroll
    for (int d = 1; d < 64; d <<= 1) r += __shfl_xor(r, d);
    __shared__ float wsum[2];
    if ((threadIdx.x & 63) == 0) wsum[threadIdx.x >> 6] = r;
    __syncthreads();
    float tot = wsum[0] + wsum[1];
    ApT[(b * 128 + j) * 128 + i] = s / (tot + 1e-6f);
}

// ---------------- weight transposes, Wm2 fragment pack, state init ----------------
__global__ void pre_init(
    const float* __restrict__ Wm1, const float* __restrict__ bm1,
    const float* __restrict__ Wm2,
    const float* __restrict__ Whr, const float* __restrict__ Whi, const float* __restrict__ Whh,
    const float* __restrict__ Wmr, const float* __restrict__ Wmi, const float* __restrict__ Wmn,
    const float* __restrict__ Wo1, const float* __restrict__ Wo2, const float* __restrict__ Wo3,
    float* __restrict__ ws)
{
    int gid = blockIdx.x * blockDim.x + threadIdx.x;
    int nth = gridDim.x * blockDim.x;
    float* WamT = ws + OFF_WAM;
    for (int idx = gid; idx < 192 * 64; idx += nth) {
        int o = idx >> 6, k = idx & 63;
        const float* src = (o < 64) ? Wmr : (o < 128) ? Wmi : Wmn;
        WamT[idx] = src[k * 64 + (o & 63)];
    }
    float* WprT = ws + OFF_WPR;
    for (int idx = gid; idx < 448 * 64; idx += nth) {
        int o = idx >> 6, k = idx & 63;
        float v;
        if (o < 128)      v = Wm1[k * 128 + o];
        else if (o < 256) v = Wm1[(64 + k) * 128 + (o - 128)];
        else {
            int oo = o - 256;
            const float* src = (oo < 64) ? Whr : (oo < 128) ? Whi : Whh;
            v = src[k * 64 + (oo & 63)];
        }
        WprT[idx] = v;
    }
    float* Wo1T = ws + OFF_WO1;
    float* Wo2T = ws + OFF_WO2;
    for (int idx = gid; idx < 4096; idx += nth) {
        int o = idx >> 6, k = idx & 63;
        Wo1T[idx] = Wo1[k * 64 + o];
        Wo2T[idx] = Wo2[k * 64 + o];
    }
    float* Wo3T = ws + OFF_WO3;
    for (int idx = gid; idx < 256; idx += nth) {
        int d = idx >> 6, k = idx & 63;
        Wo3T[idx] = Wo3[k * 4 + d];
    }
    unsigned short* Wm2f = (unsigned short*)(ws + OFF_WM2F);
    for (int idx = gid; idx < 8192; idx += nth) {
        int kt = idx >> 11, nt = (idx >> 9) & 3, ln = (idx >> 3) & 63, e = idx & 7;
        int k = kt * 32 + (ln >> 4) * 8 + e;
        int n = nt * 16 + (ln & 15);
        Wm2f[idx] = f2bf(Wm2[k * 64 + n]);
    }
    // initial state (h=0): P0 = bm1, Q0 = 0, HP0 = 0, H0 = 0, SSE = 0
    float* P0 = ws + OFF_P;
    for (int idx = gid; idx < 131072; idx += nth) P0[idx] = bm1[idx & 127];
    float* Q0 = ws + OFF_Q;
    for (int idx = gid; idx < 131072; idx += nth) Q0[idx] = 0.0f;
    float* HP0 = ws + OFF_HP;
    for (int idx = gid; idx < 196608; idx += nth) HP0[idx] = 0.0f;
    float* H0 = ws + OFF_H;
    for (int idx = gid; idx < 65536; idx += nth) H0[idx] = 0.0f;
    if (gid == 0) ws[OFF_SSE] = 0.0f;
}

// ---------------- per-step message + aggregation (the big one) ----------------
// block = (b, j); 4 waves, wave w handles i in [32w, 32w+32)
__global__ __launch_bounds__(256) void step_msg(
    const float* __restrict__ P, const float* __restrict__ Q,
    const float* __restrict__ ApT, const unsigned short* __restrict__ Wm2f,
    const float* __restrict__ bm2, float* __restrict__ agg)
{
    int blk = blockIdx.x;
    int b = blk >> 7, j = blk & 127;
    int tid = threadIdx.x;
    int lane = tid & 63, wv = tid >> 6;
    int l15 = lane & 15, g = lane >> 4;

    __shared__ __align__(16) float Qj[128];
    __shared__ float aggbuf[4][64];
    if (tid < 128) Qj[tid] = Q[(b * 128 + j) * 128 + tid];
    __syncthreads();

    f32x4 acc[2][4];
    #pragma unroll
    for (int mt = 0; mt < 2; ++mt)
        #pragma unroll
        for (int nt = 0; nt < 4; ++nt) {
            f32x4 z = {0.f, 0.f, 0.f, 0.f};
            acc[mt][nt] = z;
        }

    const float* Pb = P + (b * 128 + wv * 32) * 128;

    #pragma unroll
    for (int kt = 0; kt < 4; ++kt) {
        int k0 = kt * 32 + g * 8;
        bf16x8 bf[4];
        #pragma unroll
        for (int nt = 0; nt < 4; ++nt)
            bf[nt] = *(const bf16x8*)(Wm2f + (((kt * 4 + nt) * 64 + lane) << 3));
        bf16x8 af[2];
        f32x4 qa = *(const f32x4*)&Qj[k0];
        f32x4 qb = *(const f32x4*)&Qj[k0 + 4];
        #pragma unroll
        for (int mt = 0; mt < 2; ++mt) {
            const float* p = Pb + (mt * 16 + l15) * 128 + k0;
            f32x4 pa = *(const f32x4*)p;
            f32x4 pb = *(const f32x4*)(p + 4);
            #pragma unroll
            for (int e = 0; e < 4; ++e) {
                af[mt][e]     = (short)f2bf(fast_tanh(pa[e] + qa[e]));
                af[mt][4 + e] = (short)f2bf(fast_tanh(pb[e] + qb[e]));
            }
        }
        #pragma unroll
        for (int mt = 0; mt < 2; ++mt)
            #pragma unroll
            for (int nt = 0; nt < 4; ++nt)
                acc[mt][nt] = __builtin_amdgcn_mfma_f32_16x16x32_bf16(af[mt], bf[nt], acc[mt][nt], 0, 0, 0);
    }

    // epilogue: msg = tanh(acc + bm2), weight by ApT, reduce over i
    const float* aprow = ApT + (b * 128 + j) * 128 + wv * 32;
    float bmv[4];
    #pragma unroll
    for (int nt = 0; nt < 4; ++nt) bmv[nt] = bm2[nt * 16 + l15];
    float pagg[4] = {0.f, 0.f, 0.f, 0.f};
    #pragma unroll
    for (int mt = 0; mt < 2; ++mt) {
        float w[4];
        #pragma unroll
        for (int v = 0; v < 4; ++v) w[v] = aprow[mt * 16 + g * 4 + v];
        #pragma unroll
        for (int nt = 0; nt < 4; ++nt)
            #pragma unroll
            for (int v = 0; v < 4; ++v) {
                float msg = fast_tanh(acc[mt][nt][v] + bmv[nt]);
                pagg[nt] += w[v] * msg;
            }
    }
    #pragma unroll
    for (int nt = 0; nt < 4; ++nt) {
        pagg[nt] += __shfl_xor(pagg[nt], 16);
        pagg[nt] += __shfl_xor(pagg[nt], 32);
    }
    if (lane < 16)
        #pragma unroll
        for (int nt = 0; nt < 4; ++nt) aggbuf[wv][nt * 16 + lane] = pagg[nt];
    __syncthreads();
    if (tid < 64)
        agg[blk * 64 + tid] = aggbuf[0][tid] + aggbuf[1][tid] + aggbuf[2][tid] + aggbuf[3][tid];
}

// ---------------- per-step GRU + next-step projections + output MLP ----------------
// block handles 4 consecutive rows (same b since 4|128)
__global__ __launch_bounds__(256) void step_row(
    const float* __restrict__ X,
    const float* __restrict__ agg,
    const float* __restrict__ Hcur, const float* __restrict__ HPcur,
    float* __restrict__ Hnxt, float* __restrict__ Pnxt, float* __restrict__ Qnxt, float* __restrict__ HPnxt,
    const float* __restrict__ WamT, const float* __restrict__ WprT,
    const float* __restrict__ Wo1T, const float* __restrict__ Wo2T, const float* __restrict__ Wo3T,
    const float* __restrict__ Wir, const float* __restrict__ bir,
    const float* __restrict__ Wii, const float* __restrict__ bii,
    const float* __restrict__ Win, const float* __restrict__ bin_,
    const float* __restrict__ bm1,
    const float* __restrict__ bo1, const float* __restrict__ bo2, const float* __restrict__ bo3,
    float* __restrict__ out, float* __restrict__ sse_acc, int t)
{
    int tid = threadIdx.x;
    int R0 = blockIdx.x * 4;
    int b = R0 >> 7;
    __shared__ float sAgg[4][64], sH[4][64], sHP[4][192];
    __shared__ float sX[4][4], sTgt[4][4];
    __shared__ float sAm[4][192], sHn[4][64], sT1[4][64], sT2[4][64];
    __shared__ float sSq[16];
    {
        int r = tid >> 6, o = tid & 63;
        sAgg[r][o] = agg[(R0 + r) * 64 + o];
        sH[r][o]   = Hcur[(R0 + r) * 64 + o];
    }
    for (int idx = tid; idx < 768; idx += 256) {
        int r = idx / 192, o = idx % 192;
        sHP[r][o] = HPcur[(R0 + r) * 192 + o];
    }
    if (tid < 16) {
        int r = tid >> 2, d = tid & 3;
        int j = (R0 + r) & 127;
        sX[r][d]   = X[((b * 13 + t) * 128 + j) * 4 + d];
        sTgt[r][d] = X[((b * 13 + t + 1) * 128 + j) * 4 + d];
    }
    __syncthreads();

    // am = agg @ [Wmr|Wmi|Wmn]
    if (tid < 192) {
        const float* w = WamT + tid * 64;
        float a0 = 0, a1 = 0, a2 = 0, a3 = 0;
        #pragma unroll
        for (int k = 0; k < 64; k += 4) {
            f32x4 wv = *(const f32x4*)(w + k);
            #pragma unroll
            for (int e = 0; e < 4; ++e) {
                float ww = wv[e];
                a0 += sAgg[0][k + e] * ww; a1 += sAgg[1][k + e] * ww;
                a2 += sAgg[2][k + e] * ww; a3 += sAgg[3][k + e] * ww;
            }
        }
        sAm[0][tid] = a0; sAm[1][tid] = a1; sAm[2][tid] = a2; sAm[3][tid] = a3;
    }
    __syncthreads();

    // GRU gates
    {
        int r = tid >> 6, o = tid & 63;
        float xr = bir[o], xi = bii[o], xn = bin_[o];
        #pragma unroll
        for (int d = 0; d < 4; ++d) {
            float xv = sX[r][d];
            xr += xv * Wir[d * 64 + o];
            xi += xv * Wii[d * 64 + o];
            xn += xv * Win[d * 64 + o];
        }
        float rr = fast_sigmoid(xr + sHP[r][o]       + sAm[r][o]);
        float ig = fast_sigmoid(xi + sHP[r][64 + o]  + sAm[r][64 + o]);
        float nn = fast_tanh  (xn + rr * sHP[r][128 + o] + sAm[r][128 + o]);
        float hn = (1.0f - ig) * nn + ig * sH[r][o];
        sHn[r][o] = hn;
        Hnxt[(R0 + r) * 64 + o] = hn;
    }
    __syncthreads();

    // next-step projections: [P|Q|hr|hi|hh] = h_new @ WprT
    if (t < TSTEPS - 1) {
        for (int o = tid; o < 448; o += 256) {
            const float* w = WprT + o * 64;
            float a0 = 0, a1 = 0, a2 = 0, a3 = 0;
            #pragma unroll
            for (int k = 0; k < 64; k += 4) {
                f32x4 wv = *(const f32x4*)(w + k);
                #pragma unroll
                for (int e = 0; e < 4; ++e) {
                    float ww = wv[e];
                    a0 += sHn[0][k + e] * ww; a1 += sHn[1][k + e] * ww;
                    a2 += sHn[2][k + e] * ww; a3 += sHn[3][k + e] * ww;
                }
            }
            float bias = (o < 128) ? bm1[o] : 0.0f;
            a0 += bias; a1 += bias; a2 += bias; a3 += bias;
            if (o < 128) {
                Pnxt[(R0 + 0) * 128 + o] = a0; Pnxt[(R0 + 1) * 128 + o] = a1;
                Pnxt[(R0 + 2) * 128 + o] = a2; Pnxt[(R0 + 3) * 128 + o] = a3;
            } else if (o < 256) {
                int oo = o - 128;
                Qnxt[(R0 + 0) * 128 + oo] = a0; Qnxt[(R0 + 1) * 128 + oo] = a1;
                Qnxt[(R0 + 2) * 128 + oo] = a2; Qnxt[(R0 + 3) * 128 + oo] = a3;
            } else {
                int oo = o - 256;
                HPnxt[(R0 + 0) * 192 + oo] = a0; HPnxt[(R0 + 1) * 192 + oo] = a1;
                HPnxt[(R0 + 2) * 192 + oo] = a2; HPnxt[(R0 + 3) * 192 + oo] = a3;
            }
        }
    }

    // output MLP
    if (tid < 64) {
        const float* w = Wo1T + tid * 64;
        float a0 = 0, a1 = 0, a2 = 0, a3 = 0;
        #pragma unroll
        for (int k = 0; k < 64; k += 4) {
            f32x4 wv = *(const f32x4*)(w + k);
            #pragma unroll
            for (int e = 0; e < 4; ++e) {
                float ww = wv[e];
                a0 += sHn[0][k + e] * ww; a1 += sHn[1][k + e] * ww;
                a2 += sHn[2][k + e] * ww; a3 += sHn[3][k + e] * ww;
            }
        }
        float bb = bo1[tid];
        sT1[0][tid] = fmaxf(a0 + bb, 0.f); sT1[1][tid] = fmaxf(a1 + bb, 0.f);
        sT1[2][tid] = fmaxf(a2 + bb, 0.f); sT1[3][tid] = fmaxf(a3 + bb, 0.f);
    }
    __syncthreads();
    if (tid < 64) {
        const float* w = Wo2T + tid * 64;
        float a0 = 0, a1 = 0, a2 = 0, a3 = 0;
        #pragma unroll
        for (int k = 0; k < 64; k += 4) {
            f32x4 wv = *(const f32x4*)(w + k);
            #pragma unroll
            for (int e = 0; e < 4; ++e) {
                float ww = wv[e];
                a0 += sT1[0][k + e] * ww; a1 += sT1[1][k + e] * ww;
                a2 += sT1[2][k + e] * ww; a3 += sT1[3][k + e] * ww;
            }
        }
        float bb = bo2[tid];
        sT2[0][tid] = fmaxf(a0 + bb, 0.f); sT2[1][tid] = fmaxf(a1 + bb, 0.f);
        sT2[2][tid] = fmaxf(a2 + bb, 0.f); sT2[3][tid] = fmaxf(a3 + bb, 0.f);
    }
    __syncthreads();
    if (tid < 16) {
        int r = tid >> 2, d = tid & 3;
        const float* w = Wo3T + d * 64;
        float a = 0.f;
        #pragma unroll
        for (int k = 0; k < 64; ++k) a += sT2[r][k] * w[k];
        float p = sX[r][d] + a + bo3[d];
        int j = (R0 + r) & 127;
        out[((b * TSTEPS + t) * 128 + j) * 4 + d] = p;
        float df = sTgt[r][d] - p;
        sSq[tid] = df * df;
    }
    __syncthreads();
    if (tid == 0) {
        float s = 0.f;
        #pragma unroll
        for (int i2 = 0; i2 < 16; ++i2) s += sSq[i2];
        atomicAdd(sse_acc, s);
    }
}

// ---------------- finalize loglik ----------------
__global__ void fin(const float* __restrict__ lsg, const float* __restrict__ sse, float* __restrict__ out) {
    float ls = lsg[0];
    float sigma = fminf(fmaxf(expf(ls), 1e-4f), 10.0f);
    float c = 0.5f * 4096.0f * logf(2.0f * 3.14159265358979323846f * sigma * sigma);
    float inv2s2 = 1.0f / (2.0f * sigma * sigma);
    out[B_ * TSTEPS * N_ * D_] = -(12.0f * c + sse[0] * inv2s2);
}

extern "C" void kernel_launch(void* const* d_in, const int* in_sizes, int n_in,
                              void* d_out, int out_size, void* d_ws, size_t ws_size,
                              hipStream_t stream)
{
    const float* A    = (const float*)d_in[0];
    const float* X    = (const float*)d_in[1];
    const float* Wm1  = (const float*)d_in[2];
    const float* bm1  = (const float*)d_in[3];
    const float* Wm2  = (const float*)d_in[4];
    const float* bm2  = (const float*)d_in[5];
    const float* Wir  = (const float*)d_in[6];
    const float* bir  = (const float*)d_in[7];
    const float* Wii  = (const float*)d_in[8];
    const float* bii  = (const float*)d_in[9];
    const float* Win  = (const float*)d_in[10];
    const float* bin_ = (const float*)d_in[11];
    const float* Whr  = (const float*)d_in[12];
    const float* Whi  = (const float*)d_in[13];
    const float* Whh  = (const float*)d_in[14];
    const float* Wmr  = (const float*)d_in[15];
    const float* Wmi  = (const float*)d_in[16];
    const float* Wmn  = (const float*)d_in[17];
    const float* Wo1  = (const float*)d_in[18];
    const float* bo1  = (const float*)d_in[19];
    const float* Wo2  = (const float*)d_in[20];
    const float* bo2  = (const float*)d_in[21];
    const float* Wo3  = (const float*)d_in[22];
    const float* bo3  = (const float*)d_in[23];
    const float* lsg  = (const float*)d_in[24];
    float* ws  = (float*)d_ws;
    float* out = (float*)d_out;

    hipLaunchKernelGGL(pre_adj, dim3(1024), dim3(128), 0, stream, A, ws + OFF_APT);
    hipLaunchKernelGGL(pre_init, dim3(512), dim3(256), 0, stream,
                       Wm1, bm1, Wm2, Whr, Whi, Whh, Wmr, Wmi, Wmn, Wo1, Wo2, Wo3, ws);

    const unsigned short* Wm2f = (const unsigned short*)(ws + OFF_WM2F);
    for (int t = 0; t < TSTEPS; ++t) {
        int cur = t & 1, nxt = cur ^ 1;
        const float* Pc  = ws + OFF_P  + cur * 131072;
        const float* Qc  = ws + OFF_Q  + cur * 131072;
        const float* HPc = ws + OFF_HP + cur * 196608;
        const float* Hc  = ws + OFF_H  + cur * 65536;
        float* Pn  = ws + OFF_P  + nxt * 131072;
        float* Qn  = ws + OFF_Q  + nxt * 131072;
        float* HPn = ws + OFF_HP + nxt * 196608;
        float* Hn  = ws + OFF_H  + nxt * 65536;

        hipLaunchKernelGGL(step_msg, dim3(1024), dim3(256), 0, stream,
                           Pc, Qc, ws + OFF_APT, Wm2f, bm2, ws + OFF_AGG);
        hipLaunchKernelGGL(step_row, dim3(256), dim3(256), 0, stream,
                           X, ws + OFF_AGG, Hc, HPc, Hn, Pn, Qn, HPn,
                           ws + OFF_WAM, ws + OFF_WPR, ws + OFF_WO1, ws + OFF_WO2, ws + OFF_WO3,
                           Wir, bir, Wii, bii, Win, bin_, bm1, bo1, bo2, bo3,
                           out, ws + OFF_SSE, t);
    }
    hipLaunchKernelGGL(fin, dim3(1), dim3(1), 0, stream, lsg, ws + OFF_SSE, out);
}